// Round 1
// baseline (124.376 us; speedup 1.0000x reference)
//
#include <hip/hip_runtime.h>
#include <hip/hip_fp16.h>

// ContrastiveEmbeddingLoss, N=8192, D=128, C=100, margin=1.
//
// loss = [ sum_{y_i != y_j} d_ij  +  N*margin  +  sum_{same, i!=j} max(margin - d_ij, 0) ] / N^2
//
// Dissimilar part via the algebraic identity:
//   sum_all d      = 2N*SQ - 2*||S||^2
//   sum_same d     = sum_c ( 2 n_c SQ_c - 2 ||S_c||^2 )
// so only same-class pairs (~N^2/100) need explicit d, done with an fp16 MFMA Gram per class.

#define N_ROWS 8192
#define DIM    128
#define NCLS   100
#define MARGINV 1.0
#define CAP    224   // max staged members/class; Binom(8192,0.01) mean 82, sd 9 -> +15 sigma

typedef _Float16 half8 __attribute__((ext_vector_type(8)));
typedef float   float4v __attribute__((ext_vector_type(4)));

__global__ __launch_bounds__(256) void class_kernel(const float* __restrict__ x,
                                                    const int*   __restrict__ y,
                                                    float* __restrict__ S_c,    // [NCLS*DIM]
                                                    float* __restrict__ SQ_c,   // [NCLS]
                                                    int*   __restrict__ n_c,    // [NCLS]
                                                    float* __restrict__ hinge_c // [NCLS]
                                                    ) {
    const int c   = blockIdx.x;
    const int tid = threadIdx.x;

    __shared__ __align__(16) _Float16 xh[CAP * DIM];  // 57344 B
    __shared__ int   list[CAP];
    __shared__ float sqm[CAP];
    __shared__ float red[256];
    __shared__ int   cnt;

    if (tid == 0) cnt = 0;
    __syncthreads();

    // ---- Phase 1: collect member row indices of class c (order irrelevant) ----
    for (int i = tid; i < N_ROWS; i += 256) {
        if (y[i] == c) {
            int p = atomicAdd(&cnt, 1);
            if (p < CAP) list[p] = i;
        }
    }
    __syncthreads();
    const int mtrue = cnt;
    const int m = (mtrue < CAP) ? mtrue : CAP;
    if (tid == 0) n_c[c] = mtrue;   // true count feeds the algebraic formula

    const int ntiles = (m + 15) >> 4;
    const int mpad   = ntiles * 16;

    // ---- Phase 2: stage fp16 rows into LDS, zero-padded to tile boundary ----
    for (int idx = tid; idx < mpad * DIM; idx += 256) {
        int k = idx >> 7, d = idx & 127;
        _Float16 v = (_Float16)0.f;
        if (k < m) v = (_Float16)x[list[k] * DIM + d];
        xh[idx] = v;
    }

    // ---- Phase 3: fp32 per-dim class sums S_c and scalar SQ_c (reads global) ----
    {
        const int t = tid & 127, h = tid >> 7;
        float accS = 0.f, accQ = 0.f;
        for (int k = h; k < m; k += 2) {
            float v = x[list[k] * DIM + t];
            accS += v;
            accQ += v * v;
        }
        red[tid] = accS;
        __syncthreads();
        if (tid < 128) S_c[c * DIM + tid] = red[tid] + red[tid + 128];
        __syncthreads();
        red[tid] = accQ;
        __syncthreads();
        for (int s = 128; s > 0; s >>= 1) {
            if (tid < s) red[tid] += red[tid + s];
            __syncthreads();
        }
        if (tid == 0) SQ_c[c] = red[0];
    }

    // ---- Phase 3b: fp32 per-row squared norms (wave per row) ----
    {
        const int wave = tid >> 6, lane = tid & 63;
        for (int k = wave; k < m; k += 4) {
            const float2 v = ((const float2*)(x + list[k] * DIM))[lane];
            float s = v.x * v.x + v.y * v.y;
            #pragma unroll
            for (int off = 32; off > 0; off >>= 1) s += __shfl_xor(s, off);
            if (lane == 0) sqm[k] = s;
        }
        for (int k = m + tid; k < mpad; k += 256) sqm[k] = 0.f;
    }
    __syncthreads();

    // ---- Phase 4: Gram via mfma_f32_16x16x32_f16; hinge for ordered pairs a!=b ----
    float hacc = 0.f;
    {
        const int wave = tid >> 6, lane = tid & 63;
        const int lr = lane & 15, q = lane >> 4;
        const int ntp = ntiles * ntiles;
        for (int tp = wave; tp < ntp; tp += 4) {
            int ta = tp / ntiles, tb = tp - ta * ntiles;
            // A-frag: member (ta*16+lr), dims q*8.. ; B-frag identical shape for X*X^T
            const half8* arow = (const half8*)(xh + (ta * 16 + lr) * DIM + q * 8);
            const half8* brow = (const half8*)(xh + (tb * 16 + lr) * DIM + q * 8);
            float4v acc = {0.f, 0.f, 0.f, 0.f};
            #pragma unroll
            for (int kb = 0; kb < 4; ++kb) {
                half8 af = arow[kb * 4];   // +32 halves per K-block
                half8 bf = brow[kb * 4];
                acc = __builtin_amdgcn_mfma_f32_16x16x32_f16(af, bf, acc, 0, 0, 0);
            }
            #pragma unroll
            for (int i = 0; i < 4; ++i) {
                int a = ta * 16 + q * 4 + i;   // C/D: row = quad*4 + reg
                int b = tb * 16 + lr;          //      col = lane & 15
                if (a < m && b < m && a != b) {
                    float d = sqm[a] + sqm[b] - 2.f * acc[i];
                    d = fmaxf(d, 0.f);
                    hacc += fmaxf((float)MARGINV - d, 0.f);
                }
            }
        }
    }
    __syncthreads();
    red[tid] = hacc;
    __syncthreads();
    for (int s = 128; s > 0; s >>= 1) {
        if (tid < s) red[tid] += red[tid + s];
        __syncthreads();
    }
    if (tid == 0) hinge_c[c] = red[0];
}

__global__ __launch_bounds__(256) void finalize_kernel(const float* __restrict__ S_c,
                                                       const float* __restrict__ SQ_c,
                                                       const int*   __restrict__ n_c,
                                                       const float* __restrict__ hinge_c,
                                                       float* __restrict__ out) {
    __shared__ double dred[256];
    const int tid = threadIdx.x;

    // sum_c ||S_c||^2 = sum of squares of all entries
    double ss = 0.0;
    for (int i = tid; i < NCLS * DIM; i += 256) {
        double v = S_c[i];
        ss += v * v;
    }
    // ||S||^2 where S[d] = sum_c S_c[c][d]
    double s2 = 0.0;
    if (tid < DIM) {
        double sd = 0.0;
        for (int c = 0; c < NCLS; ++c) sd += S_c[c * DIM + tid];
        s2 = sd * sd;
    }
    double nsq = 0.0, sq = 0.0, hg = 0.0;
    if (tid < NCLS) {
        double q = SQ_c[tid];
        nsq = (double)n_c[tid] * q;
        sq  = q;
        hg  = hinge_c[tid];
    }

    auto block_reduce = [&](double v) -> double {
        dred[tid] = v;
        __syncthreads();
        for (int s = 128; s > 0; s >>= 1) {
            if (tid < s) dred[tid] += dred[tid + s];
            __syncthreads();
        }
        double r = dred[0];
        __syncthreads();
        return r;
    };

    double SS   = block_reduce(ss);    // sum_c ||S_c||^2
    double NS   = block_reduce(s2);    // ||S||^2
    double NSQ  = block_reduce(nsq);   // sum_c n_c*SQ_c
    double SQt  = block_reduce(sq);    // SQ
    double H    = block_reduce(hg);    // off-diagonal same-class hinge

    if (tid == 0) {
        const double Nf = (double)N_ROWS;
        double sum_all  = 2.0 * Nf * SQt - 2.0 * NS;
        double sum_same = 2.0 * NSQ - 2.0 * SS;
        double dissim   = sum_all - sum_same;
        double total    = dissim + Nf * (double)MARGINV + H;
        out[0] = (float)(total / (Nf * Nf));
    }
}

extern "C" void kernel_launch(void* const* d_in, const int* in_sizes, int n_in,
                              void* d_out, int out_size, void* d_ws, size_t ws_size,
                              hipStream_t stream) {
    const float* x = (const float*)d_in[0];
    const int*   y = (const int*)d_in[1];

    float* S_c     = (float*)d_ws;          // NCLS*DIM
    float* SQ_c    = S_c + NCLS * DIM;      // NCLS
    float* hinge_c = SQ_c + NCLS;           // NCLS
    int*   n_c     = (int*)(hinge_c + NCLS);// NCLS
    // total ws use: (12800 + 300) * 4 B ~= 53 KB; everything written before read,
    // so the 0xAA re-poison needs no memset.

    class_kernel<<<NCLS, 256, 0, stream>>>(x, y, S_c, SQ_c, n_c, hinge_c);
    finalize_kernel<<<1, 256, 0, stream>>>(S_c, SQ_c, n_c, hinge_c, (float*)d_out);
}

// Round 2
// 108.438 us; speedup vs baseline: 1.1470x; 1.1470x over previous
//
#include <hip/hip_runtime.h>

// ContrastiveEmbeddingLoss, N=8192, D=128, C=100, margin=1.
// loss = [ sum_{y_i!=y_j} d_ij + N*margin + sum_{same,i!=j} max(margin-d_ij,0) ] / N^2
// sum_all d  = 2N*SQ - 2||S||^2 ;  sum_same d = sum_c (2 n_c SQ_c - 2||S_c||^2)
// Only same-class pairs (~N^2/100) need explicit d -> per-class fp16 MFMA Gram.

#define N_ROWS 8192
#define DIM    128
#define NCLS   100
#define MARGINV 1.0
#define CAP    224        // Binom(8192,0.01): mean 82, sd 9 -> +15 sigma
#define LDSTRIDE 136      // halves: 272 B row stride, 16B-aligned, bank-spread
#define K1_BLOCKS 128
#define K1_ROWS  (N_ROWS / K1_BLOCKS)   // 64 rows/block
#define NT2 512

typedef _Float16 half8 __attribute__((ext_vector_type(8)));
typedef _Float16 half4v __attribute__((ext_vector_type(4)));
typedef float   float4v __attribute__((ext_vector_type(4)));

// ---------------- Kernel 1: one streaming pass over x ----------------
// Produces: sqm_g[8192] (row sqnorms), colpart[128][128] (per-block column
// sums), sqpart[128] (per-block SQ partials), cnt[100] + list[100][CAP].
__global__ __launch_bounds__(256) void scan_kernel(
    const float* __restrict__ x, const int* __restrict__ y,
    float* __restrict__ colpart, float* __restrict__ sqpart,
    float* __restrict__ sqm_g, int* __restrict__ cnt, int* __restrict__ list)
{
    const int b = blockIdx.x, tid = threadIdx.x;
    const int l = tid & 31, g = tid >> 5;       // 32 lanes per row, 8 rows/pass
    const int base = b * K1_ROWS;
    const float4* x4 = (const float4*)x;
    float4 ca = make_float4(0.f, 0.f, 0.f, 0.f);
    __shared__ float  sqred[K1_ROWS];
    __shared__ float4 colred[256];

    #pragma unroll
    for (int pass = 0; pass < K1_ROWS / 8; ++pass) {
        int r = base + pass * 8 + g;
        float4 v = x4[r * 32 + l];              // fully coalesced
        ca.x += v.x; ca.y += v.y; ca.z += v.z; ca.w += v.w;
        float s = v.x*v.x + v.y*v.y + v.z*v.z + v.w*v.w;
        s += __shfl_xor(s, 1); s += __shfl_xor(s, 2); s += __shfl_xor(s, 4);
        s += __shfl_xor(s, 8); s += __shfl_xor(s, 16);   // reduce within 32
        if (l == 0) {
            sqm_g[r] = s;
            sqred[pass * 8 + g] = s;
            int c = y[r];
            int p = atomicAdd(&cnt[c], 1);      // device-scope
            if (p < CAP) list[c * CAP + p] = r;
        }
    }
    colred[tid] = ca;
    __syncthreads();
    if (tid < 32) {
        float4 a = colred[tid];
        #pragma unroll
        for (int gg = 1; gg < 8; ++gg) {
            float4 t = colred[tid + 32 * gg];
            a.x += t.x; a.y += t.y; a.z += t.z; a.w += t.w;
        }
        ((float4*)colpart)[b * 32 + tid] = a;   // cols 4*tid..4*tid+3
        float s2 = sqred[tid] + sqred[tid + 32];
        s2 += __shfl_xor(s2, 1); s2 += __shfl_xor(s2, 2); s2 += __shfl_xor(s2, 4);
        s2 += __shfl_xor(s2, 8); s2 += __shfl_xor(s2, 16);
        if (tid == 0) sqpart[b] = s2;
    }
}

// ---------------- Kernel 2: per-class Gram hinge ----------------
__global__ __launch_bounds__(NT2) void gram_kernel(
    const float* __restrict__ x, const float* __restrict__ sqm_g,
    const int* __restrict__ cnt, const int* __restrict__ list,
    float* __restrict__ SSc, float* __restrict__ NSQc, float* __restrict__ Hc)
{
    const int c = blockIdx.x, tid = threadIdx.x;
    __shared__ __align__(16) _Float16 xh[CAP * LDSTRIDE];  // ~61 KB
    __shared__ int   llist[CAP];
    __shared__ float sqm[CAP];
    __shared__ float4 colred[NT2];
    __shared__ float  red[NT2];

    const int mtrue = cnt[c];
    const int m = mtrue < CAP ? mtrue : CAP;
    if (tid < m) llist[tid] = list[c * CAP + tid];
    __syncthreads();
    const int ntiles = (m + 15) >> 4;
    const int mpad   = ntiles << 4;

    // Single gather of class rows: float4 loads -> fp16 LDS + fp32 col sums.
    const float4* x4 = (const float4*)x;
    const int q4 = tid & 31;                    // fixed columns per thread
    float4 ca = make_float4(0.f, 0.f, 0.f, 0.f);
    for (int k = tid >> 5; k < m; k += NT2 / 32) {
        float4 v = x4[llist[k] * 32 + q4];
        ca.x += v.x; ca.y += v.y; ca.z += v.z; ca.w += v.w;
        half4v h;
        h[0] = (_Float16)v.x; h[1] = (_Float16)v.y;
        h[2] = (_Float16)v.z; h[3] = (_Float16)v.w;
        *(half4v*)(xh + k * LDSTRIDE + q4 * 4) = h;
    }
    // zero-pad rows m..mpad-1 (real 128 cols only; pad cols never read)
    for (int j = tid; j < (mpad - m) * DIM; j += NT2) {
        int rr = m + (j >> 7), d = j & 127;
        xh[rr * LDSTRIDE + d] = (_Float16)0.f;
    }
    float sv = 0.f;
    if (tid < m)        { sv = sqm_g[llist[tid]]; sqm[tid] = sv; }
    else if (tid < mpad){ sqm[tid] = 0.f; }
    colred[tid] = ca;
    red[tid] = sv;
    __syncthreads();

    // ||S_c||^2
    if (tid < 32) {
        float4 S = colred[tid];
        #pragma unroll
        for (int gg = 1; gg < NT2 / 32; ++gg) {
            float4 t = colred[tid + 32 * gg];
            S.x += t.x; S.y += t.y; S.z += t.z; S.w += t.w;
        }
        float ss = S.x*S.x + S.y*S.y + S.z*S.z + S.w*S.w;
        ss += __shfl_xor(ss, 1); ss += __shfl_xor(ss, 2); ss += __shfl_xor(ss, 4);
        ss += __shfl_xor(ss, 8); ss += __shfl_xor(ss, 16);
        if (tid == 0) SSc[c] = ss;
    }
    // SQ_c = sum sqm
    for (int s = NT2 / 2; s > 0; s >>= 1) {
        __syncthreads();
        if (tid < s) red[tid] += red[tid + s];
    }
    __syncthreads();
    if (tid == 0) NSQc[c] = (float)mtrue * red[0];

    // Gram hinge: upper-triangle tile pairs, weight 2 off-diagonal.
    float hacc = 0.f;
    {
        const int wave = tid >> 6, lane = tid & 63;
        const int lr = lane & 15, q = lane >> 4;
        const int ntp = ntiles * (ntiles + 1) / 2;
        for (int tp = wave; tp < ntp; tp += NT2 / 64) {
            int ta = 0, rem = tp;
            while (rem >= ntiles - ta) { rem -= ntiles - ta; ++ta; }
            int tb = ta + rem;
            const half8* arow = (const half8*)(xh + (ta * 16 + lr) * LDSTRIDE + q * 8);
            const half8* brow = (const half8*)(xh + (tb * 16 + lr) * LDSTRIDE + q * 8);
            float4v acc = {0.f, 0.f, 0.f, 0.f};
            #pragma unroll
            for (int kb = 0; kb < 4; ++kb)   // +32 halves per K-block
                acc = __builtin_amdgcn_mfma_f32_16x16x32_f16(arow[kb * 4], brow[kb * 4], acc, 0, 0, 0);
            float w = (ta == tb) ? 1.f : 2.f;
            #pragma unroll
            for (int i = 0; i < 4; ++i) {
                int a  = ta * 16 + q * 4 + i;   // C/D: row = quad*4 + reg
                int bb = tb * 16 + lr;          //      col = lane & 15
                if (a < m && bb < m && a != bb) {
                    float d = sqm[a] + sqm[bb] - 2.f * acc[i];
                    d = fmaxf(d, 0.f);
                    hacc += w * fmaxf((float)MARGINV - d, 0.f);
                }
            }
        }
    }
    __syncthreads();
    red[tid] = hacc;
    for (int s = NT2 / 2; s > 0; s >>= 1) {
        __syncthreads();
        if (tid < s) red[tid] += red[tid + s];
    }
    __syncthreads();
    if (tid == 0) Hc[c] = red[0];
}

// ---------------- Kernel 3: tiny finalize ----------------
__global__ __launch_bounds__(256) void final_kernel(
    const float* __restrict__ colpart, const float* __restrict__ sqpart,
    const float* __restrict__ SSc, const float* __restrict__ NSQc,
    const float* __restrict__ Hc, float* __restrict__ out)
{
    const int tid = threadIdx.x;
    __shared__ double dred[256];
    __shared__ float  Scol[DIM];
    {
        const int d = tid & 127, h = tid >> 7;  // 2 threads/column
        float s = 0.f;
        for (int b = h; b < K1_BLOCKS; b += 2) s += colpart[b * DIM + d];
        if (h == 1) Scol[d] = s;
        __syncthreads();
        if (h == 0) Scol[d] += s;
        __syncthreads();
    }
    double ns = (tid < DIM)       ? (double)Scol[tid] * (double)Scol[tid] : 0.0;
    double sq = (tid < K1_BLOCKS) ? (double)sqpart[tid] : 0.0;
    double ss = 0.0, nsq = 0.0, hg = 0.0;
    if (tid < NCLS) { ss = SSc[tid]; nsq = NSQc[tid]; hg = Hc[tid]; }

    auto br = [&](double v) -> double {
        dred[tid] = v; __syncthreads();
        for (int s = 128; s > 0; s >>= 1) {
            if (tid < s) dred[tid] += dred[tid + s];
            __syncthreads();
        }
        double r = dred[0]; __syncthreads(); return r;
    };
    double NS = br(ns), SQ = br(sq), SS = br(ss), NSQ = br(nsq), H = br(hg);
    if (tid == 0) {
        const double Nf = (double)N_ROWS;
        double sum_all  = 2.0 * Nf * SQ - 2.0 * NS;
        double sum_same = 2.0 * NSQ - 2.0 * SS;
        double total    = (sum_all - sum_same) + Nf * (double)MARGINV + H;
        out[0] = (float)(total / (Nf * Nf));
    }
}

extern "C" void kernel_launch(void* const* d_in, const int* in_sizes, int n_in,
                              void* d_out, int out_size, void* d_ws, size_t ws_size,
                              hipStream_t stream) {
    const float* x = (const float*)d_in[0];
    const int*   y = (const int*)d_in[1];

    float* colpart = (float*)d_ws;                    // 128*128
    float* sqpart  = colpart + K1_BLOCKS * DIM;       // 128
    float* sqm_g   = sqpart + K1_BLOCKS;              // 8192
    float* SSc     = sqm_g + N_ROWS;                  // 100
    float* NSQc    = SSc + NCLS;                      // 100
    float* Hc      = NSQc + NCLS;                     // 100
    int*   cnt     = (int*)(Hc + NCLS);               // 100 (needs zero)
    int*   list    = cnt + NCLS;                      // 100*CAP
    // total ws: ~190 KB; everything except cnt written before read.

    hipMemsetAsync(cnt, 0, NCLS * sizeof(int), stream);  // graph-capture legal
    scan_kernel <<<K1_BLOCKS, 256, 0, stream>>>(x, y, colpart, sqpart, sqm_g, cnt, list);
    gram_kernel <<<NCLS, NT2, 0, stream>>>(x, sqm_g, cnt, list, SSc, NSQc, Hc);
    final_kernel<<<1, 256, 0, stream>>>(colpart, sqpart, SSc, NSQc, Hc, (float*)d_out);
}